// Round 5
// baseline (165.182 us; speedup 1.0000x reference)
//
#include <hip/hip_runtime.h>
#include <hip/hip_bf16.h>

#define BB 16
#define CC 64
#define NN 4096      // H*W
#define MM 1024      // pooled spatial

typedef unsigned short u16;
typedef unsigned int u32;
typedef __attribute__((ext_vector_type(8))) short bf16x8;
typedef __attribute__((ext_vector_type(4))) float f32x4;

__device__ inline u16 f2bf(float f) {
    union { float f; u32 u; } v; v.f = f;
    return (u16)((v.u + 0x7FFFu + ((v.u >> 16) & 1u)) >> 16);
}
__device__ inline bf16x8 ld_bf16x8(const u16* p) {
    union { uint4 u; bf16x8 b; } c; c.u = *(const uint4*)p; return c.b;
}
__device__ inline bf16x8 ld2_bf16x8(const u16* p0, const u16* p1) {
    union { uint2 u[2]; bf16x8 b; } c;
    c.u[0] = *(const uint2*)p0;
    c.u[1] = *(const uint2*)p1;
    return c.b;
}
__device__ inline u32 cvt_pk_bf16(float lo, float hi) {
    __hip_bfloat162 h = __float22bfloat162_rn(make_float2(lo, hi));
    return *(u32*)&h;
}

// workspace (u16): theta_b [B][N][8] : 524288 | phi_b [B][M][8] : 131072
//                  gT_b [B][32][M]   : 524288

// ---------------------------------------------------------------------------
// Kernel 1: 1x1 convs + 2x2 maxpool -> bf16 theta/phi/gT.
// grid (16,16): block = 256 px (4 image rows), thread = 1 px, 48 fp32 accs.
// Weights read with loop-uniform addresses -> s_load_dwordx4 (SMEM/K$ path,
// no LDS, no VALU address math). x loads: 256B/wave coalesced scalar dwords.
// Pooling: horizontal shfl_xor(1) (same wave), vertical via 20KB LDS.
// ---------------------------------------------------------------------------
__global__ __launch_bounds__(256) void prep_kernel(
    const float* __restrict__ x, const float* __restrict__ w_theta,
    const float* __restrict__ w_phi, const float* __restrict__ w_g,
    u16* __restrict__ theta_b, u16* __restrict__ phi_b, u16* __restrict__ gT_b)
{
    __shared__ float pool[40 * 128];   // [k][row(4)][pooled_col(32)]

    const int t = threadIdx.x;
    const int b = blockIdx.y;
    const int nbase = blockIdx.x * 256;
    const int p = nbase + t;
    const float* xb = x + (size_t)b * CC * NN + p;

    float acc[48];
    #pragma unroll
    for (int k = 0; k < 48; ++k) acc[k] = 0.f;

    #pragma unroll 2
    for (int c4 = 0; c4 < 64; c4 += 4) {
        const float x0 = xb[(size_t)(c4 + 0) * NN];
        const float x1 = xb[(size_t)(c4 + 1) * NN];
        const float x2 = xb[(size_t)(c4 + 2) * NN];
        const float x3 = xb[(size_t)(c4 + 3) * NN];
        #pragma unroll
        for (int k = 0; k < 8; ++k) {
            const float4 wv = *(const float4*)(w_theta + k * 64 + c4);
            acc[k] += wv.x * x0 + wv.y * x1 + wv.z * x2 + wv.w * x3;
        }
        #pragma unroll
        for (int k = 0; k < 8; ++k) {
            const float4 wv = *(const float4*)(w_phi + k * 64 + c4);
            acc[8 + k] += wv.x * x0 + wv.y * x1 + wv.z * x2 + wv.w * x3;
        }
        #pragma unroll
        for (int k = 0; k < 32; ++k) {
            const float4 wv = *(const float4*)(w_g + k * 64 + c4);
            acc[16 + k] += wv.x * x0 + wv.y * x1 + wv.z * x2 + wv.w * x3;
        }
    }

    // theta: 16B/thread, fully coalesced
    {
        union { u16 s[8]; uint4 v; } tb;
        #pragma unroll
        for (int k = 0; k < 8; ++k) tb.s[k] = f2bf(acc[k]);
        *(uint4*)(theta_b + ((size_t)b * NN + p) * 8) = tb.v;
    }

    // horizontal pool (cols 2i,2i+1 = lanes 2i,2i+1 of the same wave)
    const int row = t >> 6, col = t & 63;
    float hv[40];
    #pragma unroll
    for (int k = 0; k < 40; ++k) {
        const float v = acc[8 + k];
        hv[k] = fmaxf(v, __shfl_xor(v, 1, 64));
    }
    if ((col & 1) == 0) {
        const int pc = col >> 1;
        #pragma unroll
        for (int k = 0; k < 40; ++k) pool[k * 128 + row * 32 + pc] = hv[k];
    }
    __syncthreads();

    // vertical pool: row pairs (0,1),(2,3); 2560 outputs, 10/thread
    for (int i = t; i < 2560; i += 256) {
        const int k = i >> 6, rem = i & 63, rp = rem >> 5, pcol = rem & 31;
        const float v = fmaxf(pool[k * 128 + (2 * rp) * 32 + pcol],
                              pool[k * 128 + (2 * rp + 1) * 32 + pcol]);
        const int m = (blockIdx.x * 2 + rp) * 32 + pcol;
        if (k < 8) phi_b[((size_t)b * MM + m) * 8 + k] = f2bf(v);
        else       gT_b[(size_t)b * 32 * MM + (size_t)(k - 8) * MM + m] = f2bf(v);
    }
}

// ---------------------------------------------------------------------------
// Kernel 2: fused attention + output conv + residual.
// grid (64,16), 256 threads = 4 waves; wave w owns queries qbase+16w..+15.
// phi staged ONCE in LDS (16KB, whole batch); g staged in 4 chunks of 256
// keys with register prefetch of chunk c+1 overlapping compute of chunk c.
// S^T = mfma(phi, theta); exp+pack in registers via v_cvt_pk_bf16 -> PV
// B-frag (K-permuted; g read with matching permutation). In-lane normalize,
// 5KB LDS transpose, w_o MFMA epilogue with residual.
// ---------------------------------------------------------------------------
__global__ __launch_bounds__(256, 4) void attn_out_kernel(
    const u16* __restrict__ theta_b, const u16* __restrict__ phi_b,
    const u16* __restrict__ gT_b, const float* __restrict__ w_o,
    const float* __restrict__ x, const float* __restrict__ gamma_p,
    float* __restrict__ out)
{
    __shared__ u16 phis[1024 * 8];   // 16 KB, whole batch of keys
    __shared__ u16 gs[32 * 264];     // [d][256 keys + pad8], 16.5 KB
    __shared__ u16 oS[64 * 40];      // [q_local][d + pad8], 5 KB

    const int t = threadIdx.x, w = t >> 6, lane = t & 63;
    const int m16 = lane & 15, quad = lane >> 4;
    const int b = blockIdx.y, qbase = blockIdx.x * 64;

    const u16* phg = phi_b + (size_t)b * MM * 8;
    const u16* gtg = gT_b + (size_t)b * 32 * MM;

    // stage all phi (1024 uint4, 4/thread)
    #pragma unroll
    for (int i = 0; i < 4; ++i)
        ((uint4*)phis)[i * 256 + t] = ((const uint4*)phg)[i * 256 + t];

    // persistent theta B-frag (quad0 real, rest zero)
    bf16x8 thB = {0, 0, 0, 0, 0, 0, 0, 0};
    if (quad == 0)
        thB = ld_bf16x8(theta_b + ((size_t)b * NN + qbase + w * 16 + m16) * 8);

    // persistent w_o A-frags: A[m=c][k=d]
    bf16x8 woA[4];
    #pragma unroll
    for (int cf = 0; cf < 4; ++cf) {
        const float* wp = w_o + (cf * 16 + m16) * 32 + quad * 8;
        const float4 f0 = *(const float4*)wp;
        const float4 f1 = *(const float4*)(wp + 4);
        bf16x8 a;
        a[0] = f2bf(f0.x); a[1] = f2bf(f0.y); a[2] = f2bf(f0.z); a[3] = f2bf(f0.w);
        a[4] = f2bf(f1.x); a[5] = f2bf(f1.y); a[6] = f2bf(f1.z); a[7] = f2bf(f1.w);
        woA[cf] = a;
    }

    bf16x8 onesA;
    #pragma unroll
    for (int i = 0; i < 8; ++i) onesA[i] = (short)0x3F80;

    const f32x4 zero4 = {0.f, 0.f, 0.f, 0.f};
    f32x4 oT0 = zero4, oT1 = zero4, lacc = zero4;

    // g chunk staging map: uint4 f = i*256+t -> d = f>>5, ku = f&31 (8 keys)
    uint4 r[4];
    #pragma unroll
    for (int i = 0; i < 4; ++i) {
        const int f = i * 256 + t, d = f >> 5, ku = f & 31;
        r[i] = *(const uint4*)(gtg + (size_t)d * MM + ku * 8);
    }

    for (int c = 0; c < 4; ++c) {
        __syncthreads();   // prev chunk reads done (c=0: also covers phis)
        #pragma unroll
        for (int i = 0; i < 4; ++i) {
            const int f = i * 256 + t, d = f >> 5, ku = f & 31;
            *(uint4*)(gs + d * 264 + ku * 8) = r[i];
        }
        __syncthreads();
        if (c < 3) {
            #pragma unroll
            for (int i = 0; i < 4; ++i) {
                const int f = i * 256 + t, d = f >> 5, ku = f & 31;
                r[i] = *(const uint4*)(gtg + (size_t)d * MM + (c + 1) * 256 + ku * 8);
            }
        }

        #pragma unroll
        for (int kblk = 0; kblk < 8; ++kblk) {
            const int kb = c * 256 + kblk * 32;
            bf16x8 phA0 = {0, 0, 0, 0, 0, 0, 0, 0};
            bf16x8 phA1 = {0, 0, 0, 0, 0, 0, 0, 0};
            if (quad == 0) {
                phA0 = ld_bf16x8(phis + (size_t)(kb + m16) * 8);
                phA1 = ld_bf16x8(phis + (size_t)(kb + 16 + m16) * 8);
            }
            const f32x4 Sa = __builtin_amdgcn_mfma_f32_16x16x32_bf16(phA0, thB, zero4, 0, 0, 0);
            const f32x4 Sb = __builtin_amdgcn_mfma_f32_16x16x32_bf16(phA1, thB, zero4, 0, 0, 0);

            // P B-frag in registers (K-permuted: slot j<4 -> key kblk*32+4q+j,
            // slot j>=4 -> key kblk*32+16+4q+(j-4))
            union { u32 d[4]; bf16x8 v; } pb;
            pb.d[0] = cvt_pk_bf16(__expf(Sa[0]), __expf(Sa[1]));
            pb.d[1] = cvt_pk_bf16(__expf(Sa[2]), __expf(Sa[3]));
            pb.d[2] = cvt_pk_bf16(__expf(Sb[0]), __expf(Sb[1]));
            pb.d[3] = cvt_pk_bf16(__expf(Sb[2]), __expf(Sb[3]));

            // g A-frags with the SAME key permutation
            const u16* g0p = gs + m16 * 264 + kblk * 32 + quad * 4;
            const u16* g1p = gs + (16 + m16) * 264 + kblk * 32 + quad * 4;
            const bf16x8 gA0 = ld2_bf16x8(g0p, g0p + 16);
            const bf16x8 gA1 = ld2_bf16x8(g1p, g1p + 16);

            oT0  = __builtin_amdgcn_mfma_f32_16x16x32_bf16(gA0, pb.v, oT0, 0, 0, 0);
            oT1  = __builtin_amdgcn_mfma_f32_16x16x32_bf16(gA1, pb.v, oT1, 0, 0, 0);
            lacc = __builtin_amdgcn_mfma_f32_16x16x32_bf16(onesA, pb.v, lacc, 0, 0, 0);
        }
    }

    // normalize in-lane (all rows of lacc equal l[q=m16]); transpose via oS
    const float inv = 1.0f / lacc[0];
    u16* orow = oS + (w * 16 + m16) * 40;
    {
        uint2 a, b2;
        a.x  = cvt_pk_bf16(oT0[0] * inv, oT0[1] * inv);
        a.y  = cvt_pk_bf16(oT0[2] * inv, oT0[3] * inv);
        b2.x = cvt_pk_bf16(oT1[0] * inv, oT1[1] * inv);
        b2.y = cvt_pk_bf16(oT1[2] * inv, oT1[3] * inv);
        *(uint2*)(orow + quad * 4) = a;
        *(uint2*)(orow + 16 + quad * 4) = b2;
    }
    __syncthreads();

    // output conv: D[m=c][n=px] = w_o @ o; out = gamma*D + x
    const bf16x8 oB = ld_bf16x8(oS + (w * 16 + m16) * 40 + quad * 8);
    const float gamma = *gamma_p;
    #pragma unroll
    for (int cf = 0; cf < 4; ++cf) {
        const f32x4 D = __builtin_amdgcn_mfma_f32_16x16x32_bf16(woA[cf], oB, zero4, 0, 0, 0);
        #pragma unroll
        for (int rr = 0; rr < 4; ++rr) {
            const int cch = cf * 16 + quad * 4 + rr;
            const size_t adr = ((size_t)b * CC + cch) * NN + qbase + w * 16 + m16;
            out[adr] = gamma * D[rr] + x[adr];
        }
    }
}

// ---------------------------------------------------------------------------
extern "C" void kernel_launch(void* const* d_in, const int* in_sizes, int n_in,
                              void* d_out, int out_size, void* d_ws, size_t ws_size,
                              hipStream_t stream) {
    const float* x       = (const float*)d_in[0];
    const float* w_theta = (const float*)d_in[1];
    const float* w_phi   = (const float*)d_in[2];
    const float* w_g     = (const float*)d_in[3];
    const float* w_o     = (const float*)d_in[4];
    const float* gamma   = (const float*)d_in[5];

    u16* theta_b = (u16*)d_ws;                      // 524288
    u16* phi_b   = theta_b + 524288;                // 131072
    u16* gT_b    = phi_b + 131072;                  // 524288
    float* out   = (float*)d_out;

    prep_kernel<<<dim3(16, 16), 256, 0, stream>>>(x, w_theta, w_phi, w_g,
                                                  theta_b, phi_b, gT_b);
    attn_out_kernel<<<dim3(64, 16), 256, 0, stream>>>(theta_b, phi_b, gT_b,
                                                      w_o, x, gamma, out);
}

// Round 6
// 113.742 us; speedup vs baseline: 1.4523x; 1.4523x over previous
//
#include <hip/hip_runtime.h>
#include <hip/hip_bf16.h>

#define BB 16
#define CC 64
#define NN 4096      // H*W
#define MM 1024      // pooled spatial

typedef unsigned short u16;
typedef unsigned int u32;
typedef __attribute__((ext_vector_type(8))) short bf16x8;
typedef __attribute__((ext_vector_type(4))) float f32x4;

__device__ inline u16 f2bf(float f) {
    union { float f; u32 u; } v; v.f = f;
    return (u16)((v.u + 0x7FFFu + ((v.u >> 16) & 1u)) >> 16);
}
__device__ inline bf16x8 ld_bf16x8(const u16* p) {
    union { uint4 u; bf16x8 b; } c; c.u = *(const uint4*)p; return c.b;
}
__device__ inline bf16x8 ld2_bf16x8(const u16* p0, const u16* p1) {
    union { uint2 u[2]; bf16x8 b; } c;
    c.u[0] = *(const uint2*)p0;
    c.u[1] = *(const uint2*)p1;
    return c.b;
}
__device__ inline u32 cvt_pk_bf16(float lo, float hi) {
    __hip_bfloat162 h = __float22bfloat162_rn(make_float2(lo, hi));
    return *(u32*)&h;
}

// workspace (u16): theta_b [B][N][8] : 524288 | phi_b [B][M][8] : 131072
//                  gT_b [B][32][M]   : 524288

// ---------------------------------------------------------------------------
// Kernel 1: MFMA 1x1 convs + 2x2 maxpool -> bf16 theta/phi/gT.
// grid (16,16): block = 256 px (4 image rows). Conv = [48 x 64] @ [64 x px]
// via 16x16x32 bf16 MFMA. Out-ch frags: f0 = theta(rows 0-7 = quads 0,1) +
// phi(rows 8-15 = quads 2,3); f1 = g[0:16); f2 = g[16:32).
// Wave w owns px cols w*16..w*16+15 of all 4 rows (r-tiles) -> horizontal
// pool = shfl_xor(1), vertical pool = in-lane max across r-tiles.
// Weights: 6 A-frags in registers (24 VGPRs), zero LDS. x: direct global
// dword loads (channel-major == B-frag layout), cvt_pk to bf16 in-reg.
// ---------------------------------------------------------------------------
__global__ __launch_bounds__(256) void prep_kernel(
    const float* __restrict__ x, const float* __restrict__ w_theta,
    const float* __restrict__ w_phi, const float* __restrict__ w_g,
    u16* __restrict__ theta_b, u16* __restrict__ phi_b, u16* __restrict__ gT_b)
{
    const int t = threadIdx.x, w = t >> 6, lane = t & 63;
    const int m16 = lane & 15, quad = lane >> 4;
    const int b = blockIdx.y, bx = blockIdx.x;
    const int nbase = bx * 256;

    // ---- A-frags: A[m=out-ch][k=in-ch], a[j] = W[m16][kc*32+quad*8+j] ----
    bf16x8 A[3][2];
    {
        const float* row0 = (m16 < 8) ? (w_theta + m16 * 64) : (w_phi + (m16 - 8) * 64);
        const float* rows[3] = { row0, w_g + m16 * 64, w_g + (16 + m16) * 64 };
        #pragma unroll
        for (int f = 0; f < 3; ++f) {
            #pragma unroll
            for (int kc = 0; kc < 2; ++kc) {
                const float* p = rows[f] + kc * 32 + quad * 8;
                const float4 f0 = *(const float4*)p;
                const float4 f1 = *(const float4*)(p + 4);
                union { u32 d[4]; bf16x8 v; } a;
                a.d[0] = cvt_pk_bf16(f0.x, f0.y);
                a.d[1] = cvt_pk_bf16(f0.z, f0.w);
                a.d[2] = cvt_pk_bf16(f1.x, f1.y);
                a.d[3] = cvt_pk_bf16(f1.z, f1.w);
                A[f][kc] = a.v;
            }
        }
    }

    const float* xb = x + (size_t)b * CC * NN;
    const f32x4 zero4 = {0.f, 0.f, 0.f, 0.f};
    f32x4 acc[4][3];
    #pragma unroll
    for (int r = 0; r < 4; ++r)
        #pragma unroll
        for (int f = 0; f < 3; ++f) acc[r][f] = zero4;

    #pragma unroll
    for (int r = 0; r < 4; ++r) {
        const int px = nbase + r * 64 + w * 16 + m16;
        #pragma unroll
        for (int kc = 0; kc < 2; ++kc) {
            float xv[8];
            #pragma unroll
            for (int j = 0; j < 8; ++j)
                xv[j] = xb[(size_t)(kc * 32 + quad * 8 + j) * NN + px];
            union { u32 d[4]; bf16x8 v; } bxf;
            bxf.d[0] = cvt_pk_bf16(xv[0], xv[1]);
            bxf.d[1] = cvt_pk_bf16(xv[2], xv[3]);
            bxf.d[2] = cvt_pk_bf16(xv[4], xv[5]);
            bxf.d[3] = cvt_pk_bf16(xv[6], xv[7]);
            #pragma unroll
            for (int f = 0; f < 3; ++f)
                acc[r][f] = __builtin_amdgcn_mfma_f32_16x16x32_bf16(A[f][kc], bxf.v, acc[r][f], 0, 0, 0);
        }
    }

    // ---- theta: frag0 quads 0,1 (ch = quad*4+rr), full-res ----
    if (quad < 2) {
        #pragma unroll
        for (int r = 0; r < 4; ++r) {
            const int px = nbase + r * 64 + w * 16 + m16;
            uint2 v;
            v.x = cvt_pk_bf16(acc[r][0][0], acc[r][0][1]);
            v.y = cvt_pk_bf16(acc[r][0][2], acc[r][0][3]);
            *(uint2*)(theta_b + ((size_t)b * NN + px) * 8 + quad * 4) = v;
        }
    }

    // ---- pooling (all lanes run shuffles; results valid on even m16) ----
    float pv[2][3][4];   // [rp][f][rr]
    #pragma unroll
    for (int f = 0; f < 3; ++f)
        #pragma unroll
        for (int rr = 0; rr < 4; ++rr) {
            float h0 = acc[0][f][rr]; h0 = fmaxf(h0, __shfl_xor(h0, 1, 64));
            float h1 = acc[1][f][rr]; h1 = fmaxf(h1, __shfl_xor(h1, 1, 64));
            float h2 = acc[2][f][rr]; h2 = fmaxf(h2, __shfl_xor(h2, 1, 64));
            float h3 = acc[3][f][rr]; h3 = fmaxf(h3, __shfl_xor(h3, 1, 64));
            pv[0][f][rr] = fmaxf(h0, h1);
            pv[1][f][rr] = fmaxf(h2, h3);
        }

    if ((m16 & 1) == 0) {
        const int pcol = w * 8 + (m16 >> 1);
        #pragma unroll
        for (int rp = 0; rp < 2; ++rp) {
            const int m = (2 * bx + rp) * 32 + pcol;
            if (quad >= 2) {   // phi ch = (quad-2)*4 + rr
                uint2 v;
                v.x = cvt_pk_bf16(pv[rp][0][0], pv[rp][0][1]);
                v.y = cvt_pk_bf16(pv[rp][0][2], pv[rp][0][3]);
                *(uint2*)(phi_b + ((size_t)b * MM + m) * 8 + (quad - 2) * 4) = v;
            }
            #pragma unroll
            for (int f = 1; f < 3; ++f)
                #pragma unroll
                for (int rr = 0; rr < 4; ++rr) {
                    const int d = (f - 1) * 16 + quad * 4 + rr;
                    gT_b[(size_t)b * 32 * MM + (size_t)d * MM + m] = f2bf(pv[rp][f][rr]);
                }
        }
    }
}

// ---------------------------------------------------------------------------
// Kernel 2: fused attention + output conv + residual (unchanged from R5).
// grid (64,16), 256 threads = 4 waves; wave w owns queries qbase+16w..+15.
// ---------------------------------------------------------------------------
__global__ __launch_bounds__(256, 4) void attn_out_kernel(
    const u16* __restrict__ theta_b, const u16* __restrict__ phi_b,
    const u16* __restrict__ gT_b, const float* __restrict__ w_o,
    const float* __restrict__ x, const float* __restrict__ gamma_p,
    float* __restrict__ out)
{
    __shared__ u16 phis[1024 * 8];   // 16 KB, whole batch of keys
    __shared__ u16 gs[32 * 264];     // [d][256 keys + pad8], 16.5 KB
    __shared__ u16 oS[64 * 40];      // [q_local][d + pad8], 5 KB

    const int t = threadIdx.x, w = t >> 6, lane = t & 63;
    const int m16 = lane & 15, quad = lane >> 4;
    const int b = blockIdx.y, qbase = blockIdx.x * 64;

    const u16* phg = phi_b + (size_t)b * MM * 8;
    const u16* gtg = gT_b + (size_t)b * 32 * MM;

    #pragma unroll
    for (int i = 0; i < 4; ++i)
        ((uint4*)phis)[i * 256 + t] = ((const uint4*)phg)[i * 256 + t];

    bf16x8 thB = {0, 0, 0, 0, 0, 0, 0, 0};
    if (quad == 0)
        thB = ld_bf16x8(theta_b + ((size_t)b * NN + qbase + w * 16 + m16) * 8);

    bf16x8 woA[4];
    #pragma unroll
    for (int cf = 0; cf < 4; ++cf) {
        const float* wp = w_o + (cf * 16 + m16) * 32 + quad * 8;
        const float4 f0 = *(const float4*)wp;
        const float4 f1 = *(const float4*)(wp + 4);
        union { u32 d[4]; bf16x8 v; } a;
        a.d[0] = cvt_pk_bf16(f0.x, f0.y);
        a.d[1] = cvt_pk_bf16(f0.z, f0.w);
        a.d[2] = cvt_pk_bf16(f1.x, f1.y);
        a.d[3] = cvt_pk_bf16(f1.z, f1.w);
        woA[cf] = a.v;
    }

    bf16x8 onesA;
    #pragma unroll
    for (int i = 0; i < 8; ++i) onesA[i] = (short)0x3F80;

    const f32x4 zero4 = {0.f, 0.f, 0.f, 0.f};
    f32x4 oT0 = zero4, oT1 = zero4, lacc = zero4;

    uint4 r[4];
    #pragma unroll
    for (int i = 0; i < 4; ++i) {
        const int f = i * 256 + t, d = f >> 5, ku = f & 31;
        r[i] = *(const uint4*)(gtg + (size_t)d * MM + ku * 8);
    }

    for (int c = 0; c < 4; ++c) {
        __syncthreads();
        #pragma unroll
        for (int i = 0; i < 4; ++i) {
            const int f = i * 256 + t, d = f >> 5, ku = f & 31;
            *(uint4*)(gs + d * 264 + ku * 8) = r[i];
        }
        __syncthreads();
        if (c < 3) {
            #pragma unroll
            for (int i = 0; i < 4; ++i) {
                const int f = i * 256 + t, d = f >> 5, ku = f & 31;
                r[i] = *(const uint4*)(gtg + (size_t)d * MM + (c + 1) * 256 + ku * 8);
            }
        }

        #pragma unroll
        for (int kblk = 0; kblk < 8; ++kblk) {
            const int kb = c * 256 + kblk * 32;
            bf16x8 phA0 = {0, 0, 0, 0, 0, 0, 0, 0};
            bf16x8 phA1 = {0, 0, 0, 0, 0, 0, 0, 0};
            if (quad == 0) {
                phA0 = ld_bf16x8(phis + (size_t)(kb + m16) * 8);
                phA1 = ld_bf16x8(phis + (size_t)(kb + 16 + m16) * 8);
            }
            const f32x4 Sa = __builtin_amdgcn_mfma_f32_16x16x32_bf16(phA0, thB, zero4, 0, 0, 0);
            const f32x4 Sb = __builtin_amdgcn_mfma_f32_16x16x32_bf16(phA1, thB, zero4, 0, 0, 0);

            union { u32 d[4]; bf16x8 v; } pb;
            pb.d[0] = cvt_pk_bf16(__expf(Sa[0]), __expf(Sa[1]));
            pb.d[1] = cvt_pk_bf16(__expf(Sa[2]), __expf(Sa[3]));
            pb.d[2] = cvt_pk_bf16(__expf(Sb[0]), __expf(Sb[1]));
            pb.d[3] = cvt_pk_bf16(__expf(Sb[2]), __expf(Sb[3]));

            const u16* g0p = gs + m16 * 264 + kblk * 32 + quad * 4;
            const u16* g1p = gs + (16 + m16) * 264 + kblk * 32 + quad * 4;
            const bf16x8 gA0 = ld2_bf16x8(g0p, g0p + 16);
            const bf16x8 gA1 = ld2_bf16x8(g1p, g1p + 16);

            oT0  = __builtin_amdgcn_mfma_f32_16x16x32_bf16(gA0, pb.v, oT0, 0, 0, 0);
            oT1  = __builtin_amdgcn_mfma_f32_16x16x32_bf16(gA1, pb.v, oT1, 0, 0, 0);
            lacc = __builtin_amdgcn_mfma_f32_16x16x32_bf16(onesA, pb.v, lacc, 0, 0, 0);
        }
    }

    const float inv = 1.0f / lacc[0];
    u16* orow = oS + (w * 16 + m16) * 40;
    {
        uint2 a, b2;
        a.x  = cvt_pk_bf16(oT0[0] * inv, oT0[1] * inv);
        a.y  = cvt_pk_bf16(oT0[2] * inv, oT0[3] * inv);
        b2.x = cvt_pk_bf16(oT1[0] * inv, oT1[1] * inv);
        b2.y = cvt_pk_bf16(oT1[2] * inv, oT1[3] * inv);
        *(uint2*)(orow + quad * 4) = a;
        *(uint2*)(orow + 16 + quad * 4) = b2;
    }
    __syncthreads();

    const bf16x8 oB = ld_bf16x8(oS + (w * 16 + m16) * 40 + quad * 8);
    const float gamma = *gamma_p;
    #pragma unroll
    for (int cf = 0; cf < 4; ++cf) {
        const f32x4 D = __builtin_amdgcn_mfma_f32_16x16x32_bf16(woA[cf], oB, zero4, 0, 0, 0);
        #pragma unroll
        for (int rr = 0; rr < 4; ++rr) {
            const int cch = cf * 16 + quad * 4 + rr;
            const size_t adr = ((size_t)b * CC + cch) * NN + qbase + w * 16 + m16;
            out[adr] = gamma * D[rr] + x[adr];
        }
    }
}

// ---------------------------------------------------------------------------
extern "C" void kernel_launch(void* const* d_in, const int* in_sizes, int n_in,
                              void* d_out, int out_size, void* d_ws, size_t ws_size,
                              hipStream_t stream) {
    const float* x       = (const float*)d_in[0];
    const float* w_theta = (const float*)d_in[1];
    const float* w_phi   = (const float*)d_in[2];
    const float* w_g     = (const float*)d_in[3];
    const float* w_o     = (const float*)d_in[4];
    const float* gamma   = (const float*)d_in[5];

    u16* theta_b = (u16*)d_ws;                      // 524288
    u16* phi_b   = theta_b + 524288;                // 131072
    u16* gT_b    = phi_b + 131072;                  // 524288
    float* out   = (float*)d_out;

    prep_kernel<<<dim3(16, 16), 256, 0, stream>>>(x, w_theta, w_phi, w_g,
                                                  theta_b, phi_b, gT_b);
    attn_out_kernel<<<dim3(64, 16), 256, 0, stream>>>(theta_b, phi_b, gT_b,
                                                      w_o, x, gamma, out);
}